// Round 13
// baseline (88.135 us; speedup 1.0000x reference)
//
#include <hip/hip_runtime.h>
#include <stdint.h>

typedef float  f32x4  __attribute__((ext_vector_type(4)));
typedef short  bf16x8 __attribute__((ext_vector_type(8)));
typedef int    i32x4  __attribute__((ext_vector_type(4)));
typedef unsigned int u32x2 __attribute__((ext_vector_type(2)));

#define C1f 0.70710678118654752f
#define C2f 0.5f
#define C3f 0.35355339059327373f

#define NT 512          // 8 waves
#define CH 64           // chunk rows
#define RB 1040         // LDS row stride bytes (512*2 + 16 pad)
#define CHSZ (CH*RB)    // 66560 B
#define RPB 256         // rows per block
#define NCHUNK (RPB/CH) // 4
#define NCOLG 4         // col groups (128 cols each)

__device__ __forceinline__ unsigned int f2b(float f) {
    unsigned int u; __builtin_memcpy(&u, &f, 4);
    u += 0x7fffu + ((u >> 16) & 1u);          // RTNE f32 -> bf16
    return u >> 16;
}
__device__ __forceinline__ unsigned int pack2(float lo, float hi) {
    return f2b(lo) | (f2b(hi) << 16);
}
__device__ __forceinline__ bf16x8 cast8(i32x4 v) {
    bf16x8 r; __builtin_memcpy(&r, &v, 16); return r;
}

// LDS-only barrier: orders ds ops across the workgroup WITHOUT draining vmcnt.
__device__ __forceinline__ void lds_barrier() {
    asm volatile("s_waitcnt lgkmcnt(0)" ::: "memory");
    __builtin_amdgcn_s_barrier();
    __builtin_amdgcn_sched_barrier(0);
}
// wait until <=4 vmem ops outstanding (the 4 newest = this chunk's out-stores)
__device__ __forceinline__ void vwait4() {
    asm volatile("s_waitcnt vmcnt(4)" ::: "memory");
    __builtin_amdgcn_sched_barrier(0);
}

// G[o][i0..i0+7] as bf16x8.  G = composed DWT -> blockdiag(W) -> IDWT matrix:
// G[o][i] = 1/8*Wa[o/8][i/8] + 1/8*s2(o)s2(i)*W2[o/8][i/8]
//         + 1/4*s1(o)s1(i)*W1[o/4][i/4] + 1/2*s0(o)s0(i)*W0[o/2][i/2]
__device__ __forceinline__ bf16x8 g_frag(int o, int i0,
        const float* __restrict__ W0, const float* __restrict__ W1,
        const float* __restrict__ W2, const float* __restrict__ Wa)
{
    const float s0o = (o & 1) ? -1.f : 1.f;
    const float s1o = ((o >> 1) & 1) ? -1.f : 1.f;
    const float s2o = ((o >> 2) & 1) ? -1.f : 1.f;
    const float4 w0 = *(const float4*)(W0 + (o >> 1) * 256 + (i0 >> 1));
    const float2 w1 = *(const float2*)(W1 + (o >> 2) * 128 + (i0 >> 2));
    const float  w2 = W2[(o >> 3) * 64 + (i0 >> 3)];
    const float  wa = Wa[(o >> 3) * 64 + (i0 >> 3)];
    const float base = 0.125f * wa;
    const float c2   = 0.125f * s2o * w2;
    const float c1   = 0.25f  * s1o;
    const float c0   = 0.5f   * s0o;
    const float w0a[4] = { w0.x, w0.y, w0.z, w0.w };
    const float w1a[2] = { w1.x, w1.y };
    float g[8];
    #pragma unroll
    for (int e = 0; e < 8; ++e) {
        const float t2 = ((e >> 2) & 1) ? -c2 : c2;
        const float t1 = (((e >> 1) & 1) ? -c1 : c1) * w1a[e >> 2];
        const float t0 = ((e & 1) ? -c0 : c0) * w0a[e >> 1];
        g[e] = base + t2 + t1 + t0;
    }
    i32x4 p = { (int)pack2(g[0],g[1]), (int)pack2(g[2],g[3]),
                (int)pack2(g[4],g[5]), (int)pack2(g[6],g[7]) };
    return cast8(p);
}

// prep: build G in MFMA-fragment blob order + bias vector g.
__global__ void prep(const float* __restrict__ W0, const float* __restrict__ b0,
                     const float* __restrict__ W1, const float* __restrict__ b1,
                     const float* __restrict__ W2, const float* __restrict__ b2,
                     const float* __restrict__ Wa, const float* __restrict__ ba,
                     unsigned short* __restrict__ ws)
{
    const int gid  = blockIdx.x * 256 + threadIdx.x;   // 32768 threads
    const int blob = gid >> 6, lane = gid & 63;
    const int otg  = blob >> 4, ks = blob & 15;
    const int o  = otg * 16 + (lane & 15);
    const int i0 = ks * 32 + ((lane >> 4) * 8);
    bf16x8 f = g_frag(o, i0, W0, W1, W2, Wa);
    i32x4 p; __builtin_memcpy(&p, &f, 16);
    *(i32x4*)(ws + blob * 512 + lane * 8) = p;
    if (gid < 512) {
        float* gv = (float*)(ws + 262144);
        const int oo = gid;
        const float s0 = (oo & 1) ? -C1f : C1f;
        const float s1 = ((oo >> 1) & 1) ? -C2f : C2f;
        const float s2 = ((oo >> 2) & 1) ? -C3f : C3f;
        gv[oo] = C3f * ba[oo >> 3] + s2 * b2[oo >> 3] + s1 * b1[oo >> 2] + s0 * b0[oo >> 1];
    }
}

// main: out = x @ G^T + g.  Block: 256 rows x 128 cols, 8 waves; wave owns ONE
// 16-col tile with full-K G in regs (loaded once).  x streams via double-buffered
// 64-row LDS chunks (133KB LDS): only 5 barriers per block, 256KB of loads in
// flight per chunk => HBM queue stays deep while waves wait.  lgkm-only barriers;
// counted vmcnt leaves out-stores draining in background.  XCD-chunked swizzle
// co-locates the 4 col-groups of the same rows on one XCD (x shared via L2/L3).
template<int USE_WS>
__global__ __launch_bounds__(NT, 2)
void wavelet_gemm(const float* __restrict__ x,
                  const float* __restrict__ W0, const float* __restrict__ b0,
                  const float* __restrict__ W1, const float* __restrict__ b1,
                  const float* __restrict__ W2, const float* __restrict__ b2,
                  const float* __restrict__ Wa, const float* __restrict__ ba,
                  const unsigned short* __restrict__ wsb,
                  float* __restrict__ out, int nblk)
{
    __shared__ char lds[2 * CHSZ];        // 133120 B

    const int tid  = threadIdx.x;
    const int lane = tid & 63;
    const int wave = tid >> 6;            // 0..7

    // XCD-chunked bijective swizzle (nblk % 8 == 0)
    const int cpx = nblk >> 3;
    const int lbid = ((int)blockIdx.x & 7) * cpx + ((int)blockIdx.x >> 3);
    const int colg = lbid & (NCOLG - 1);
    const long rowblk = (long)(lbid >> 2) * RPB;

    const int otg  = colg * 8 + wave;     // global col-tile 0..31
    const int col0 = otg * 16;
    const int bc0  = col0 + ((lane >> 4) << 2);   // this lane's 4 out cols

    // ---- B: this wave's full-K G fragments, loaded once (64 regs) ----
    bf16x8 B[16];
    if (USE_WS) {
        #pragma unroll
        for (int ks = 0; ks < 16; ++ks)
            B[ks] = cast8(*(const i32x4*)(wsb + ((size_t)(otg * 16 + ks) * 512) + lane * 8));
    } else {
        #pragma unroll
        for (int ks = 0; ks < 16; ++ks)
            B[ks] = g_frag(col0 + (lane & 15), ks * 32 + ((lane >> 4) * 8), W0, W1, W2, Wa);
    }
    #pragma unroll
    for (int ks = 0; ks < 16; ++ks) {     // pin: no re-issue inside the loop
        i32x4 t; __builtin_memcpy(&t, &B[ks], 16);
        asm volatile("" : "+v"(t));
        __builtin_memcpy(&B[ks], &t, 16);
    }

    // bias for this lane's 4 cols
    f32x4 gv4;
    if (USE_WS) {
        const float4 g4 = *(const float4*)((const float*)(wsb + 262144) + bc0);
        gv4 = f32x4{ g4.x, g4.y, g4.z, g4.w };
    } else {
        #pragma unroll
        for (int j = 0; j < 4; ++j) {
            const int col = bc0 + j;
            const float s0 = (col & 1) ? -C1f : C1f;
            const float s1 = ((col >> 1) & 1) ? -C2f : C2f;
            const float s2 = ((col >> 2) & 1) ? -C3f : C3f;
            gv4[j] = C3f * ba[col >> 3] + s2 * b2[col >> 3] + s1 * b1[col >> 2] + s0 * b0[col >> 1];
        }
    }

    // chunk = 64 rows x 512 f32 = 8192 float4; 16 per thread
    auto ldx = [&](int c, f32x4* v) {
        const f32x4* xb = (const f32x4*)(x + (rowblk + (long)c * CH) * 512);
        #pragma unroll
        for (int i = 0; i < 16; ++i) v[i] = xb[i * NT + tid];
    };
    auto stx = [&](int c, const f32x4* v) {
        char* base = lds + (c & 1) * CHSZ;
        #pragma unroll
        for (int i = 0; i < 16; ++i) {
            const int f = i * NT + tid;
            const int row = f >> 7, c4 = f & 127;
            u32x2 p = { pack2(v[i][0], v[i][1]), pack2(v[i][2], v[i][3]) };
            *(u32x2*)(base + row * RB + c4 * 8) = p;
        }
    };
    // compute one 64-row chunk: 4 m-subtiles x 16 ks MFMAs + 4 out f32x4 stores
    auto compute = [&](int c) {
        const char* base = lds + (c & 1) * CHSZ + (lane & 15) * RB + ((lane >> 4) * 16);
        const long r0 = rowblk + (long)c * CH + (lane & 15);
        #pragma unroll
        for (int m = 0; m < 4; ++m) {
            const char* pa = base + m * 16 * RB;
            f32x4 acc = {};
            #pragma unroll
            for (int ks = 0; ks < 16; ++ks) {
                bf16x8 a = cast8(*(const i32x4*)(pa + ks * 64));
                acc = __builtin_amdgcn_mfma_f32_16x16x32_bf16(B[ks], a, acc, 0, 0, 0);
            }
            *(f32x4*)(out + (r0 + m * 16) * 512 + bc0) = acc + gv4;
        }
    };

    // ---- prologue ----
    {
        f32x4 v[16];
        ldx(0, v);
        stx(0, v);                        // compiler inserts the vm wait for v
    }
    lds_barrier();

    // ---- main loop: 4 chunks, depth-1 pipeline, 5 barriers total ----
    #pragma unroll 1
    for (int c = 0; c < NCHUNK; ++c) {
        f32x4 vn[16];
        if (c + 1 < NCHUNK) {
            ldx(c + 1, vn);               // 16 loads issued early (256KB/block in flight)
            __builtin_amdgcn_sched_barrier(0);
        }
        compute(c);                       // 64 ds_read_b128 + 64 MFMA + 4 stores
        if (c + 1 < NCHUNK) {
            vwait4();                     // loads drained; 4 out-stores stay in flight
            stx(c + 1, vn);
            lds_barrier();
        }
    }
}

extern "C" void kernel_launch(void* const* d_in, const int* in_sizes, int n_in,
                              void* d_out, int out_size, void* d_ws, size_t ws_size,
                              hipStream_t stream)
{
    const float* x  = (const float*)d_in[0];
    const float* W0 = (const float*)d_in[1];
    const float* b0 = (const float*)d_in[2];
    const float* W1 = (const float*)d_in[3];
    const float* b1 = (const float*)d_in[4];
    const float* W2 = (const float*)d_in[5];
    const float* b2 = (const float*)d_in[6];
    const float* Wa = (const float*)d_in[7];
    const float* ba = (const float*)d_in[8];
    float* out = (float*)d_out;

    const int nrows = in_sizes[0] / 512;          // 65536
    const int nblk  = (nrows / RPB) * NCOLG;      // 1024

    if (ws_size >= (size_t)(524288 + 2048)) {
        unsigned short* ws = (unsigned short*)d_ws;
        prep<<<128, 256, 0, stream>>>(W0, b0, W1, b1, W2, b2, Wa, ba, ws);
        wavelet_gemm<1><<<nblk, NT, 0, stream>>>(x, W0, b0, W1, b1, W2, b2, Wa, ba, ws, out, nblk);
    } else {
        wavelet_gemm<0><<<nblk, NT, 0, stream>>>(x, W0, b0, W1, b1, W2, b2, Wa, ba, nullptr, out, nblk);
    }
}

// Round 14
// 75.720 us; speedup vs baseline: 1.1640x; 1.1640x over previous
//
#include <hip/hip_runtime.h>
#include <stdint.h>

typedef float  f32x4  __attribute__((ext_vector_type(4)));
typedef short  bf16x8 __attribute__((ext_vector_type(8)));
typedef int    i32x4  __attribute__((ext_vector_type(4)));
typedef unsigned int u32x2 __attribute__((ext_vector_type(2)));

#define C1f 0.70710678118654752f
#define C2f 0.5f
#define C3f 0.35355339059327373f

#define NT 512          // 8 waves
#define CH 32           // chunk rows
#define RB 1040         // LDS row stride bytes (512*2 + 16 pad)
#define CHSZ (CH*RB)    // 33280 B
#define RPB 256         // rows per block
#define NCHUNK (RPB/CH) // 8

__device__ __forceinline__ unsigned int f2b(float f) {
    unsigned int u; __builtin_memcpy(&u, &f, 4);
    u += 0x7fffu + ((u >> 16) & 1u);          // RTNE f32 -> bf16
    return u >> 16;
}
__device__ __forceinline__ unsigned int pack2(float lo, float hi) {
    return f2b(lo) | (f2b(hi) << 16);
}
__device__ __forceinline__ bf16x8 cast8(i32x4 v) {
    bf16x8 r; __builtin_memcpy(&r, &v, 16); return r;
}

// LDS-only barrier: orders ds ops across the workgroup WITHOUT draining vmcnt.
__device__ __forceinline__ void lds_barrier() {
    asm volatile("s_waitcnt lgkmcnt(0)" ::: "memory");
    __builtin_amdgcn_s_barrier();
    __builtin_amdgcn_sched_barrier(0);
}
// wait until <=4 vmem ops outstanding (4 newest = this chunk's out-stores)
__device__ __forceinline__ void vwait4() {
    asm volatile("s_waitcnt vmcnt(4)" ::: "memory");
    __builtin_amdgcn_sched_barrier(0);
}

// G[o][i0..i0+7] as bf16x8.  G = composed DWT -> blockdiag(W) -> IDWT matrix:
// G[o][i] = 1/8*Wa[o/8][i/8] + 1/8*s2(o)s2(i)*W2[o/8][i/8]
//         + 1/4*s1(o)s1(i)*W1[o/4][i/4] + 1/2*s0(o)s0(i)*W0[o/2][i/2]
__device__ __forceinline__ bf16x8 g_frag(int o, int i0,
        const float* __restrict__ W0, const float* __restrict__ W1,
        const float* __restrict__ W2, const float* __restrict__ Wa)
{
    const float s0o = (o & 1) ? -1.f : 1.f;
    const float s1o = ((o >> 1) & 1) ? -1.f : 1.f;
    const float s2o = ((o >> 2) & 1) ? -1.f : 1.f;
    const float4 w0 = *(const float4*)(W0 + (o >> 1) * 256 + (i0 >> 1));
    const float2 w1 = *(const float2*)(W1 + (o >> 2) * 128 + (i0 >> 2));
    const float  w2 = W2[(o >> 3) * 64 + (i0 >> 3)];
    const float  wa = Wa[(o >> 3) * 64 + (i0 >> 3)];
    const float base = 0.125f * wa;
    const float c2   = 0.125f * s2o * w2;
    const float c1   = 0.25f  * s1o;
    const float c0   = 0.5f   * s0o;
    const float w0a[4] = { w0.x, w0.y, w0.z, w0.w };
    const float w1a[2] = { w1.x, w1.y };
    float g[8];
    #pragma unroll
    for (int e = 0; e < 8; ++e) {
        const float t2 = ((e >> 2) & 1) ? -c2 : c2;
        const float t1 = (((e >> 1) & 1) ? -c1 : c1) * w1a[e >> 2];
        const float t0 = ((e & 1) ? -c0 : c0) * w0a[e >> 1];
        g[e] = base + t2 + t1 + t0;
    }
    i32x4 p = { (int)pack2(g[0],g[1]), (int)pack2(g[2],g[3]),
                (int)pack2(g[4],g[5]), (int)pack2(g[6],g[7]) };
    return cast8(p);
}

// prep: build G in MFMA-fragment blob order + bias vector g.
// blob = otg*16 + ks (512 blobs); lane holds G[o=otg*16+(lane&15)][k=ks*32+(lane>>4)*8+e].
__global__ void prep(const float* __restrict__ W0, const float* __restrict__ b0,
                     const float* __restrict__ W1, const float* __restrict__ b1,
                     const float* __restrict__ W2, const float* __restrict__ b2,
                     const float* __restrict__ Wa, const float* __restrict__ ba,
                     unsigned short* __restrict__ ws)
{
    const int gid  = blockIdx.x * 256 + threadIdx.x;   // 32768 threads
    const int blob = gid >> 6, lane = gid & 63;
    const int otg  = blob >> 4, ks = blob & 15;
    const int o  = otg * 16 + (lane & 15);
    const int i0 = ks * 32 + ((lane >> 4) * 8);
    bf16x8 f = g_frag(o, i0, W0, W1, W2, Wa);
    i32x4 p; __builtin_memcpy(&p, &f, 16);
    *(i32x4*)(ws + blob * 512 + lane * 8) = p;
    if (gid < 512) {
        float* gv = (float*)(ws + 262144);
        const int oo = gid;
        const float s0 = (oo & 1) ? -C1f : C1f;
        const float s1 = ((oo >> 1) & 1) ? -C2f : C2f;
        const float s2 = ((oo >> 2) & 1) ? -C3f : C3f;
        gv[oo] = C3f * ba[oo >> 3] + s2 * b2[oo >> 3] + s1 * b1[oo >> 2] + s0 * b0[oo >> 1];
    }
}

// main: out = x @ G^T + g.  Block: 256 rows x 256 cols (col-half), 8 waves.
// Wave owns TWO adjacent 16-col tiles (B = 32 frags = 128 regs, loaded once):
// each LDS A-read feeds 2 MFMAs -> chip LDS traffic halves vs 1 tile/wave.
// x streams via double-buffered 32-row LDS chunks; lgkm-only barriers; counted
// vmcnt leaves out-stores in flight.  XCD swizzle pairs the two col-halves of
// the same rows on one XCD (x shared via L2/L3).
template<int USE_WS>
__global__ __launch_bounds__(NT, 2)
void wavelet_gemm(const float* __restrict__ x,
                  const float* __restrict__ W0, const float* __restrict__ b0,
                  const float* __restrict__ W1, const float* __restrict__ b1,
                  const float* __restrict__ W2, const float* __restrict__ b2,
                  const float* __restrict__ Wa, const float* __restrict__ ba,
                  const unsigned short* __restrict__ wsb,
                  float* __restrict__ out, int nblk)
{
    __shared__ char lds[2 * CHSZ];        // 66560 B

    const int tid  = threadIdx.x;
    const int lane = tid & 63;
    const int wave = tid >> 6;            // 0..7

    // XCD-chunked bijective swizzle (nblk % 8 == 0); chalf is fastest-varying
    // so both halves of the same row-range run adjacently on one XCD.
    const int cpx = nblk >> 3;
    const int lbid = ((int)blockIdx.x & 7) * cpx + ((int)blockIdx.x >> 3);
    const int chalf = lbid & 1;
    const long rowblk = (long)(lbid >> 1) * RPB;

    const int otg0 = chalf * 16 + wave * 2;   // first of two col-tiles
    const int col0 = otg0 * 16;
    const int bc0  = col0 + ((lane >> 4) << 2);   // lane's 4 cols in tile 0

    // ---- B: two col-tiles' full-K G fragments, loaded once (128 regs) ----
    bf16x8 B0[16], B1[16];
    if (USE_WS) {
        #pragma unroll
        for (int ks = 0; ks < 16; ++ks) {
            B0[ks] = cast8(*(const i32x4*)(wsb + ((size_t)(otg0 * 16 + ks) * 512) + lane * 8));
            B1[ks] = cast8(*(const i32x4*)(wsb + ((size_t)((otg0 + 1) * 16 + ks) * 512) + lane * 8));
        }
    } else {
        #pragma unroll
        for (int ks = 0; ks < 16; ++ks) {
            B0[ks] = g_frag(col0 + (lane & 15),      ks * 32 + ((lane >> 4) * 8), W0, W1, W2, Wa);
            B1[ks] = g_frag(col0 + 16 + (lane & 15), ks * 32 + ((lane >> 4) * 8), W0, W1, W2, Wa);
        }
    }
    #pragma unroll
    for (int ks = 0; ks < 16; ++ks) {     // pin: no re-issue inside the loop
        i32x4 t0, t1;
        __builtin_memcpy(&t0, &B0[ks], 16);
        __builtin_memcpy(&t1, &B1[ks], 16);
        asm volatile("" : "+v"(t0), "+v"(t1));
        __builtin_memcpy(&B0[ks], &t0, 16);
        __builtin_memcpy(&B1[ks], &t1, 16);
    }

    // bias for this lane's 4 cols in each tile
    f32x4 gv40, gv41;
    if (USE_WS) {
        const float4 g0 = *(const float4*)((const float*)(wsb + 262144) + bc0);
        const float4 g1 = *(const float4*)((const float*)(wsb + 262144) + bc0 + 16);
        gv40 = f32x4{ g0.x, g0.y, g0.z, g0.w };
        gv41 = f32x4{ g1.x, g1.y, g1.z, g1.w };
    } else {
        #pragma unroll
        for (int j = 0; j < 4; ++j) {
            #pragma unroll
            for (int t = 0; t < 2; ++t) {
                const int col = bc0 + t * 16 + j;
                const float s0 = (col & 1) ? -C1f : C1f;
                const float s1 = ((col >> 1) & 1) ? -C2f : C2f;
                const float s2 = ((col >> 2) & 1) ? -C3f : C3f;
                const float v = C3f * ba[col >> 3] + s2 * b2[col >> 3] + s1 * b1[col >> 2] + s0 * b0[col >> 1];
                if (t == 0) gv40[j] = v; else gv41[j] = v;
            }
        }
    }

    // chunk = 32 rows x 512 f32 = 4096 float4; 8 per thread
    auto ldx = [&](int c, f32x4* v) {
        const f32x4* xb = (const f32x4*)(x + (rowblk + (long)c * CH) * 512);
        #pragma unroll
        for (int i = 0; i < 8; ++i) v[i] = xb[i * NT + tid];
    };
    auto stx = [&](int c, const f32x4* v) {
        char* base = lds + (c & 1) * CHSZ;
        #pragma unroll
        for (int i = 0; i < 8; ++i) {
            const int f = i * NT + tid;
            const int row = f >> 7, c4 = f & 127;
            u32x2 p = { pack2(v[i][0], v[i][1]), pack2(v[i][2], v[i][3]) };
            *(u32x2*)(base + row * RB + c4 * 8) = p;
        }
    };
    // compute one 32-row chunk: 2 m-subtiles x 16 ks, each A-read feeds 2 MFMAs
    auto compute = [&](int c) {
        const char* base = lds + (c & 1) * CHSZ + (lane & 15) * RB + ((lane >> 4) * 16);
        const long r0 = rowblk + (long)c * CH + (lane & 15);
        #pragma unroll
        for (int m = 0; m < 2; ++m) {
            const char* pa = base + m * 16 * RB;
            f32x4 acc0 = {}, acc1 = {};
            #pragma unroll
            for (int ks = 0; ks < 16; ++ks) {
                bf16x8 a = cast8(*(const i32x4*)(pa + ks * 64));
                acc0 = __builtin_amdgcn_mfma_f32_16x16x32_bf16(B0[ks], a, acc0, 0, 0, 0);
                acc1 = __builtin_amdgcn_mfma_f32_16x16x32_bf16(B1[ks], a, acc1, 0, 0, 0);
            }
            const long rr = (r0 + m * 16) * 512;
            *(f32x4*)(out + rr + bc0)      = acc0 + gv40;
            *(f32x4*)(out + rr + bc0 + 16) = acc1 + gv41;
        }
    };

    // ---- prologue ----
    {
        f32x4 v[8];
        ldx(0, v);
        stx(0, v);                        // compiler inserts the vm wait for v
    }
    lds_barrier();

    // ---- main loop: depth-1 pipeline, counted vmcnt, lgkm-only barriers ----
    #pragma unroll 1
    for (int c = 0; c < NCHUNK; ++c) {
        f32x4 vn[8];
        if (c + 1 < NCHUNK) {
            ldx(c + 1, vn);               // 8 loads issued early
            __builtin_amdgcn_sched_barrier(0);
        }
        compute(c);                       // 32 ds_read_b128 + 64 MFMA + 4 stores
        if (c + 1 < NCHUNK) {
            vwait4();                     // loads drained; 4 out-stores in flight
            stx(c + 1, vn);
        }
        lds_barrier();
    }
}

extern "C" void kernel_launch(void* const* d_in, const int* in_sizes, int n_in,
                              void* d_out, int out_size, void* d_ws, size_t ws_size,
                              hipStream_t stream)
{
    const float* x  = (const float*)d_in[0];
    const float* W0 = (const float*)d_in[1];
    const float* b0 = (const float*)d_in[2];
    const float* W1 = (const float*)d_in[3];
    const float* b1 = (const float*)d_in[4];
    const float* W2 = (const float*)d_in[5];
    const float* b2 = (const float*)d_in[6];
    const float* Wa = (const float*)d_in[7];
    const float* ba = (const float*)d_in[8];
    float* out = (float*)d_out;

    const int nrows = in_sizes[0] / 512;      // 65536
    const int nblk  = (nrows / RPB) * 2;      // 512 (row-groups x col-halves)

    if (ws_size >= (size_t)(524288 + 2048)) {
        unsigned short* ws = (unsigned short*)d_ws;
        prep<<<128, 256, 0, stream>>>(W0, b0, W1, b1, W2, b2, Wa, ba, ws);
        wavelet_gemm<1><<<nblk, NT, 0, stream>>>(x, W0, b0, W1, b1, W2, b2, Wa, ba, ws, out, nblk);
    } else {
        wavelet_gemm<0><<<nblk, NT, 0, stream>>>(x, W0, b0, W1, b1, W2, b2, Wa, ba, nullptr, out, nblk);
    }
}